// Round 11
// baseline (275.552 us; speedup 1.0000x reference)
//
#include <hip/hip_runtime.h>

// Geometry fixed by the reference.
constexpr int Dd  = 96;
constexpr int Hh  = 160;
constexpr int Ww  = 160;
constexpr int HW  = Hh * Ww;       // 25600
constexpr int DHW = Dd * HW;       // 2,457,600

// 4 voxels (consecutive x) per thread: 1024 voxels per 256-thread block.
constexpr int NG   = DHW / 1024;   // 2400 blocks
constexpr int GCH  = NG / 8;       // 300 (XCD z-chunk swizzle, bijective)

// remap: normalize(/(s-1)) + grid_sample(align_corners=False) collapse to
//   sample = (voxel + disp*rf) * s/(s-1) - 0.5
constexpr float KZ = 96.0f / 95.0f;
constexpr float KY = 160.0f / 159.0f;
constexpr float KX = 160.0f / 159.0f;

__device__ __forceinline__ int iclamp(int v, int lo, int hi) {
    return min(max(v, lo), hi);
}

// bf16 <-> f32 (RNE)
__device__ __forceinline__ float bf2f(unsigned short u) {
    return __uint_as_float(((unsigned)u) << 16);
}
__device__ __forceinline__ unsigned short f2bf(float f) {
    unsigned u = __float_as_uint(f);
    return (unsigned short)((u + 0x7FFFu + ((u >> 16) & 1u)) >> 16);
}

// Per-axis floor + validity-folded weights (zeros padding -> weight zeroed
// when corner out of bounds; index clamped so loads stay in-range).
struct Ax { int i0; float w0, w1; };
__device__ __forceinline__ Ax axis_setup(float s, int n) {
    float f = floorf(s);
    int i0 = (int)f;
    float t = s - f;
    Ax a;
    a.i0 = i0;
    a.w0 = (i0 >= 0 && i0 < n) ? 1.0f - t : 0.0f;
    a.w1 = (i0 + 1 >= 0 && i0 + 1 < n) ? t : 0.0f;
    return a;
}

// Pack planar [3,DHW] f32 flow -> [DHW] ushort4 bf16 (w unused). 4 voxels/thread.
__global__ __launch_bounds__(256) void pack_bf16(
        const float* __restrict__ f, ushort4* __restrict__ out)
{
    int i = blockIdx.x * blockDim.x + threadIdx.x;    // group of 4 voxels
    const float4* p0 = (const float4*)f;
    const float4* p1 = (const float4*)(f + DHW);
    const float4* p2 = (const float4*)(f + 2 * DHW);
    float4 a = p0[i], b = p1[i], c = p2[i];
    ushort4 o;
    o = make_ushort4(f2bf(a.x), f2bf(b.x), f2bf(c.x), 0); out[4 * i + 0] = o;
    o = make_ushort4(f2bf(a.y), f2bf(b.y), f2bf(c.y), 0); out[4 * i + 1] = o;
    o = make_ushort4(f2bf(a.z), f2bf(b.z), f2bf(c.z), 0); out[4 * i + 2] = o;
    o = make_ushort4(f2bf(a.w), f2bf(b.w), f2bf(c.w), 0); out[4 * i + 3] = o;
}

// One trilinear gather from a bf16x4 volume; returns 3 accumulated channels.
__device__ __forceinline__ void gather_bf(
        const ushort4* __restrict__ vol,
        int d, int h, int w, float fd, float fh, float fw, float rf,
        float& a0, float& a1, float& a2)
{
    Ax az = axis_setup(((float)d + fd * rf) * KZ - 0.5f, Dd);
    Ax ay = axis_setup(((float)h + fh * rf) * KY - 0.5f, Hh);
    Ax ax = axis_setup(((float)w + fw * rf) * KX - 0.5f, Ww);
    float wz[2] = {az.w0, az.w1};
    float wy[2] = {ay.w0, ay.w1};
    float wx[2] = {ax.w0, ax.w1};
    int cz[2] = {iclamp(az.i0, 0, Dd - 1) * HW, iclamp(az.i0 + 1, 0, Dd - 1) * HW};
    int cy[2] = {iclamp(ay.i0, 0, Hh - 1) * Ww, iclamp(ay.i0 + 1, 0, Hh - 1) * Ww};
    int cx[2] = {iclamp(ax.i0, 0, Ww - 1),      iclamp(ax.i0 + 1, 0, Ww - 1)};
    a0 = 0.0f; a1 = 0.0f; a2 = 0.0f;
#pragma unroll
    for (int dz = 0; dz < 2; ++dz)
#pragma unroll
        for (int dy = 0; dy < 2; ++dy)
#pragma unroll
            for (int dx = 0; dx < 2; ++dx) {
                float wk = wz[dz] * wy[dy] * wx[dx];
                ushort4 v = vol[cz[dz] + cy[dy] + cx[dx]];
                a0 += wk * bf2f(v.x);
                a1 += wk * bf2f(v.y);
                a2 += wk * bf2f(v.z);
            }
}

// One trilinear gather from an f32 scalar volume.
__device__ __forceinline__ float gather_f32(
        const float* __restrict__ vol,
        int d, int h, int w, float fd, float fh, float fw, float rf)
{
    Ax az = axis_setup(((float)d + fd * rf) * KZ - 0.5f, Dd);
    Ax ay = axis_setup(((float)h + fh * rf) * KY - 0.5f, Hh);
    Ax ax = axis_setup(((float)w + fw * rf) * KX - 0.5f, Ww);
    float wz[2] = {az.w0, az.w1};
    float wy[2] = {ay.w0, ay.w1};
    float wx[2] = {ax.w0, ax.w1};
    int cz[2] = {iclamp(az.i0, 0, Dd - 1) * HW, iclamp(az.i0 + 1, 0, Dd - 1) * HW};
    int cy[2] = {iclamp(ay.i0, 0, Hh - 1) * Ww, iclamp(ay.i0 + 1, 0, Hh - 1) * Ww};
    int cx[2] = {iclamp(ax.i0, 0, Ww - 1),      iclamp(ax.i0 + 1, 0, Ww - 1)};
    float acc = 0.0f;
#pragma unroll
    for (int dz = 0; dz < 2; ++dz)
#pragma unroll
        for (int dy = 0; dy < 2; ++dy)
#pragma unroll
            for (int dx = 0; dx < 2; ++dx) {
                float wk = wz[dz] * wy[dy] * wx[dx];
                acc += wk * vol[cz[dz] + cy[dy] + cx[dx]];
            }
    return acc;
}

// out = trilinear_sample(src_bf16, voxel + dvf*rf) + dvf ; 4 voxels/thread.
__global__ __launch_bounds__(256) void compose_bf4(
        const ushort4* __restrict__ src,      // [DHW] bf16x4 (d,h,w,_)
        const float*   __restrict__ dvf,      // [3,DHW] planar f32
        const float*   __restrict__ rf_ptr,
        uint4* __restrict__ out)              // [DHW/2] = bf16x4 pairs
{
    int b = (blockIdx.x & 7) * GCH + (blockIdx.x >> 3);
    int g = b * 256 + threadIdx.x;            // group of 4 consecutive voxels
    int idx = g * 4;
    float rf = *rf_ptr;

    int d = idx / HW;
    int rem = idx - d * HW;
    int h = rem / Ww;
    int w = rem - h * Ww;                     // w % 4 == 0, row-aligned

    float4 fd4 = ((const float4*)dvf)[g];
    float4 fh4 = ((const float4*)(dvf + DHW))[g];
    float4 fw4 = ((const float4*)(dvf + 2 * DHW))[g];
    float fds[4] = {fd4.x, fd4.y, fd4.z, fd4.w};
    float fhs[4] = {fh4.x, fh4.y, fh4.z, fh4.w};
    float fws[4] = {fw4.x, fw4.y, fw4.z, fw4.w};

    unsigned r[4][2];
#pragma unroll
    for (int j = 0; j < 4; ++j) {
        float a0, a1, a2;
        gather_bf(src, d, h, w + j, fds[j], fhs[j], fws[j], rf, a0, a1, a2);
        r[j][0] = (unsigned)f2bf(a0 + fds[j]) | ((unsigned)f2bf(a1 + fhs[j]) << 16);
        r[j][1] = (unsigned)f2bf(a2 + fws[j]);
    }
    out[2 * g]     = make_uint4(r[0][0], r[0][1], r[1][0], r[1][1]);
    out[2 * g + 1] = make_uint4(r[2][0], r[2][1], r[3][0], r[3][1]);
}

// Fused stages 3+4, 4 voxels/thread:
//   composed3 = sample(composed2_bf16, voxel + final*rf) + final -> out_flow (f32)
//   out_img   = sample(src_f32, voxel + composed3*rf)
__global__ __launch_bounds__(256) void final_fused4(
        const ushort4* __restrict__ composed2, // [DHW] bf16x4
        const float*   __restrict__ fflow,     // [3,DHW] planar f32
        const float*   __restrict__ src,       // [DHW] f32
        const float*   __restrict__ rf_ptr,
        float* __restrict__ out_flow,          // [3,DHW] planar f32
        float* __restrict__ out_img)           // [DHW] f32
{
    int b = (blockIdx.x & 7) * GCH + (blockIdx.x >> 3);
    int g = b * 256 + threadIdx.x;
    int idx = g * 4;
    float rf = *rf_ptr;

    int d = idx / HW;
    int rem = idx - d * HW;
    int h = rem / Ww;
    int w = rem - h * Ww;

    float4 fd4 = ((const float4*)fflow)[g];
    float4 fh4 = ((const float4*)(fflow + DHW))[g];
    float4 fw4 = ((const float4*)(fflow + 2 * DHW))[g];
    float fds[4] = {fd4.x, fd4.y, fd4.z, fd4.w};
    float fhs[4] = {fh4.x, fh4.y, fh4.z, fh4.w};
    float fws[4] = {fw4.x, fw4.y, fw4.z, fw4.w};

    float c0s[4], c1s[4], c2s[4];
#pragma unroll
    for (int j = 0; j < 4; ++j) {
        float a0, a1, a2;
        gather_bf(composed2, d, h, w + j, fds[j], fhs[j], fws[j], rf, a0, a1, a2);
        c0s[j] = a0 + fds[j];
        c1s[j] = a1 + fhs[j];
        c2s[j] = a2 + fws[j];
    }
    ((float4*)(out_flow))[g]           = make_float4(c0s[0], c0s[1], c0s[2], c0s[3]);
    ((float4*)(out_flow + DHW))[g]     = make_float4(c1s[0], c1s[1], c1s[2], c1s[3]);
    ((float4*)(out_flow + 2 * DHW))[g] = make_float4(c2s[0], c2s[1], c2s[2], c2s[3]);

    float img[4];
#pragma unroll
    for (int j = 0; j < 4; ++j) {
        img[j] = gather_f32(src, d, h, w + j, c0s[j], c1s[j], c2s[j], rf);
    }
    ((float4*)out_img)[g] = make_float4(img[0], img[1], img[2], img[3]);
}

extern "C" void kernel_launch(void* const* d_in, const int* in_sizes, int n_in,
                              void* d_out, int out_size, void* d_ws, size_t ws_size,
                              hipStream_t stream) {
    const float* src        = (const float*)d_in[0];   // [1,1,D,H,W]
    const float* flow_list  = (const float*)d_in[1];   // [3,1,3,D,H,W]
    const float* final_flow = (const float*)d_in[2];   // [1,3,D,H,W]
    const float* rf         = (const float*)d_in[3];   // scalar

    float* out_img  = (float*)d_out;          // deform_2_img: [DHW]
    float* out_flow = (float*)d_out + DHW;    // out_flow (== composed3): [3,DHW]

    ushort4* bufA = (ushort4*)d_ws;           // [DHW] bf16x4
    ushort4* bufB = bufA + DHW;               // [DHW] bf16x4
    ushort4* bufC = bufB + DHW;               // [DHW] bf16x4 (f0 packed)

    const float* f0 = flow_list;
    const float* f1 = flow_list + 3 * (size_t)DHW;
    const float* f2 = flow_list + 6 * (size_t)DHW;

    dim3 block(256);

    // bufC = bf16-packed f0   (streaming)
    pack_bf16<<<dim3(NG), block, 0, stream>>>(f0, bufC);
    // bufB = composed1 = warp(f0, grid(f1)) + f1
    compose_bf4<<<dim3(NG), block, 0, stream>>>(bufC, f1, rf, (uint4*)bufB);
    // bufA = composed2 = warp(composed1, grid(f2)) + f2
    compose_bf4<<<dim3(NG), block, 0, stream>>>(bufB, f2, rf, (uint4*)bufA);
    // out_flow = composed3 ; out_img = warp(src, grid(composed3))
    final_fused4<<<dim3(NG), block, 0, stream>>>(bufA, final_flow, src, rf,
                                                 out_flow, out_img);
}